// Round 11
// baseline (54.779 us; speedup 1.0000x reference)
//
#include <hip/hip_runtime.h>
#include <hip/hip_bf16.h>
#include <math.h>

#define BB 4
#define EE 8192
#define NN 1024
#define FF 512
#define DD 512
#define ALPHA 0.2f
#define SLOTS 64
#define NGEMM 256
#define NEX 8192   // 4 waves/block, 1 edge/wave

typedef __attribute__((ext_vector_type(8))) short short8;
typedef __attribute__((ext_vector_type(4))) float f32x4;

static __device__ __forceinline__ float leaky(float x) { return x > 0.f ? x : ALPHA * x; }

static __device__ __forceinline__ float wave_sum(float v) {
#pragma unroll
    for (int m = 32; m >= 1; m >>= 1) v += __shfl_xor(v, m);
    return v;
}
static __device__ __forceinline__ float wave_max(float v) {
#pragma unroll
    for (int m = 32; m >= 1; m >>= 1) v = fmaxf(v, __shfl_xor(v, m));
    return v;
}
static __device__ __forceinline__ short8 cvt8(float4 a, float4 b) {
    __hip_bfloat16 t[8];
    t[0] = __float2bfloat16(a.x); t[1] = __float2bfloat16(a.y);
    t[2] = __float2bfloat16(a.z); t[3] = __float2bfloat16(a.w);
    t[4] = __float2bfloat16(b.x); t[5] = __float2bfloat16(b.y);
    t[6] = __float2bfloat16(b.z); t[7] = __float2bfloat16(b.w);
    return *(short8*)t;
}
static __device__ __forceinline__ float b2f(short s) {
    unsigned u = ((unsigned)(unsigned short)s) << 16;
    float f;
    __builtin_memcpy(&f, &u, 4);
    return f;
}
static __device__ __forceinline__ short f2b(float f) {
    __hip_bfloat16 h = __float2bfloat16(f);
    short s;
    __builtin_memcpy(&s, &h, 2);
    return s;
}
// locate the nonzero within a 2-subchunk (256-elem) window of uint2 loads; -1 if absent
static __device__ __forceinline__ int find2u2(uint2 a, uint2 b, int lane) {
    unsigned za = a.x | a.y, zb = b.x | b.y;
    unsigned long long m = __ballot((za | zb) != 0u);
    if (!m) return -1;
    int il = za ? (lane * 2 + (a.x ? 0 : 1)) : (128 + lane * 2 + (b.x ? 0 : 1));
    return __shfl(il, (int)__ffsll(m) - 1);
}
// locate within a single 128-elem uint2 chunk; -1 if absent
static __device__ __forceinline__ int find1u2(uint2 v, int lane) {
    unsigned nz = v.x | v.y;
    unsigned long long m = __ballot(nz != 0u);
    if (!m) return -1;
    int il = lane * 2 + (v.x ? 0 : 1);
    return __shfl(il, (int)__ffsll(m) - 1);
}

// ---------------- K1 (mega): gemm (self-staged B, p-epilogue) + extract ----------------
#define BM 128
#define BN 64
#define BK 32
__global__ __launch_bounds__(256) void k_mega(const float* __restrict__ nodes,
                                              const float* __restrict__ w,
                                              const float* __restrict__ attn,
                                              const float* __restrict__ C,
                                              const float* __restrict__ Nm,
                                              short* __restrict__ Z16,
                                              float* __restrict__ p1, float* __restrict__ p2,
                                              int* __restrict__ cur, int* __restrict__ sDst) {
    __shared__ short As[BM][BK + 8];
    __shared__ short Bs[BN][BK + 8];
    int bx = blockIdx.x;
    int t = threadIdx.x;
    int lane = t & 63;
    if (bx < NGEMM) {
        // ---- GEMM: Z16 = bf16(nodes) @ bf16(w), B staged straight from w ----
        int m0 = (bx & 31) * BM;
        int n0 = (bx >> 5) * BN;
        int wid = t >> 6;
        int wm = wid & 1, wn = wid >> 1;
        int bc = t & 63, bkr = t >> 6;  // B staging: col, row-group
        f32x4 acc[4][2] = {};
        for (int k0 = 0; k0 < FF; k0 += BK) {
#pragma unroll
            for (int s = 0; s < 2; s++) {
                int cid = t + s * 256;
                int r = cid >> 2, cc = cid & 3;
                const float4* ap = (const float4*)&nodes[(size_t)(m0 + r) * FF + k0 + cc * 8];
                *(short8*)&As[r][cc * 8] = cvt8(ap[0], ap[1]);
            }
            {
                // stage B transposed: Bs[c][kk] = bf16(w[k0+kk][n0+c])
                short tmpb[8];
#pragma unroll
                for (int i = 0; i < 8; i++)
                    tmpb[i] = f2b(w[(size_t)(k0 + bkr * 8 + i) * DD + n0 + bc]);
                *(short8*)&Bs[bc][bkr * 8] = *(short8*)tmpb;
            }
            __syncthreads();
            short8 af[4];
            short8 bf[2];
#pragma unroll
            for (int m = 0; m < 4; m++)
                af[m] = *(const short8*)&As[wm * 64 + m * 16 + (lane & 15)][(lane >> 4) * 8];
#pragma unroll
            for (int n = 0; n < 2; n++)
                bf[n] = *(const short8*)&Bs[wn * 32 + n * 16 + (lane & 15)][(lane >> 4) * 8];
#pragma unroll
            for (int m = 0; m < 4; m++)
#pragma unroll
                for (int n = 0; n < 2; n++)
                    acc[m][n] = __builtin_amdgcn_mfma_f32_16x16x32_bf16(af[m], bf[n], acc[m][n], 0, 0, 0);
            __syncthreads();
        }
        // epilogue: Z16 store + p1/p2 partial dots (fp32 acc x attention cols)
        float a1c[2], a2c[2];
#pragma unroll
        for (int n = 0; n < 2; n++) {
            int col = n0 + wn * 32 + n * 16 + (lane & 15);
            a1c[n] = attn[col];
            a2c[n] = attn[DD + col];
        }
#pragma unroll
        for (int m = 0; m < 4; m++) {
#pragma unroll
            for (int n = 0; n < 2; n++)
#pragma unroll
                for (int r = 0; r < 4; r++) {
                    int row = m0 + wm * 64 + m * 16 + (lane >> 4) * 4 + r;
                    int col = n0 + wn * 32 + n * 16 + (lane & 15);
                    Z16[(size_t)row * DD + col] = f2b(acc[m][n][r]);
                }
#pragma unroll
            for (int r = 0; r < 4; r++) {
                float v1 = acc[m][0][r] * a1c[0] + acc[m][1][r] * a1c[1];
                float v2 = acc[m][0][r] * a2c[0] + acc[m][1][r] * a2c[1];
#pragma unroll
                for (int mm = 8; mm >= 1; mm >>= 1) {
                    v1 += __shfl_xor(v1, mm);
                    v2 += __shfl_xor(v2, mm);
                }
                if ((lane & 15) == 0) {
                    int row = m0 + wm * 64 + m * 16 + (lane >> 4) * 4 + r;
                    atomicAdd(&p1[row], v1);
                    atomicAdd(&p2[row], v2);
                }
            }
        }
        return;
    }
    // ---- extract + scatter: one wave per edge; 512B uint2 chunks, 2-chunk window + seq ----
    int widx = (bx - NGEMM) * 4 + (t >> 6);
    const uint2* rc = (const uint2*)(C + (size_t)widx * NN);
    const uint2* rn = (const uint2*)(Nm + (size_t)widx * NN);
    uint2 a0 = rc[lane], a1 = rc[64 + lane];
    uint2 b0 = rn[lane], b1 = rn[64 + lane];
    int s = find2u2(a0, a1, lane);
    int d = find2u2(b0, b1, lane);
#pragma unroll 1
    for (int c = 2; c < 8 && (s < 0 || d < 0); ++c) {
        uint2 va, vb;
        bool needS = s < 0, needD = d < 0;
        if (needS) va = rc[c * 64 + lane];
        if (needD) vb = rn[c * 64 + lane];
        if (needS) {
            int r = find1u2(va, lane);
            if (r >= 0) s = c * 128 + r;
        }
        if (needD) {
            int r = find1u2(vb, lane);
            if (r >= 0) d = c * 128 + r;
        }
    }
    if (lane == 0) {
        int b = widx >> 13;  // EE = 8192
        int row = b * NN + s;
        int pos = atomicAdd(&cur[row], 1);
        if (pos < SLOTS) sDst[row * SLOTS + pos] = d;
    }
}

// ---------------- K2: per-row softmax (exact keras-mask emulation) + output ----------------
__global__ __launch_bounds__(256) void k_out(const int* __restrict__ cur,
                                             const int* __restrict__ sDst,
                                             const float* __restrict__ p1,
                                             const float* __restrict__ p2,
                                             const short* __restrict__ Z16,
                                             float* __restrict__ out) {
    int rid = (blockIdx.x * 256 + threadIdx.x) >> 6;  // one wave per (b,i)
    int lane = threadIdx.x & 63;
    if (rid >= BB * NN) return;
    int K = cur[rid];
    K = K > SLOTS ? SLOTS : K;
    int base = rid * SLOTS;
    int b = rid >> 10;
    float* op = out + (size_t)rid * DD + lane * 8;
    if (K == 0) {
        float4 z4 = {0.f, 0.f, 0.f, 0.f};
        *(float4*)op = z4;
        *(float4*)(op + 4) = z4;
        return;
    }
    float p1row = p1[rid];
    int de = (lane < K) ? sDst[base + lane] : -1;
    float ae = (lane < K) ? leaky(p1row + p2[(b << 10) + de]) : 0.f;
    float S = 0.f;
    int c = 0, firstk = 64;
    for (int k = 0; k < K; k++) {
        int dk = __shfl(de, k);
        float ak = __shfl(ae, k);
        bool mt = (lane < K) && (dk == de);
        if (mt) {
            S += ak;
            c++;
            if (k < firstk) firstk = k;
        }
    }
    float logit = (lane < K) ? (S + (float)(c - 1) * 1e9f) : -INFINITY;
    float M = wave_max(logit);
    float contrib = (lane < K && firstk == lane) ? __expf(logit - M) : 0.f;
    float Dsum = wave_sum(contrib);
    float wgt = (lane < K) ? __expf(logit - M) / Dsum : 0.f;
    const short* Zb = Z16 + ((size_t)(b << 10)) * DD;
    float acc[8] = {0.f, 0.f, 0.f, 0.f, 0.f, 0.f, 0.f, 0.f};
#pragma unroll
    for (int k = 0; k < 32; k++) {
        if (k >= K) break;  // wave-uniform break
        int dj = __shfl(de, k);
        float wk = __shfl(wgt, k);
        short8 zv = *(const short8*)(Zb + (size_t)dj * DD + lane * 8);
#pragma unroll
        for (int j = 0; j < 8; j++) acc[j] += wk * b2f(zv[j]);
    }
    for (int k = 32; k < K; k++) {
        int dj = __shfl(de, k);
        float wk = __shfl(wgt, k);
        short8 zv = *(const short8*)(Zb + (size_t)dj * DD + lane * 8);
#pragma unroll
        for (int j = 0; j < 8; j++) acc[j] += wk * b2f(zv[j]);
    }
    float4 o0, o1;
    o0.x = leaky(acc[0]); o0.y = leaky(acc[1]); o0.z = leaky(acc[2]); o0.w = leaky(acc[3]);
    o1.x = leaky(acc[4]); o1.y = leaky(acc[5]); o1.z = leaky(acc[6]); o1.w = leaky(acc[7]);
    *(float4*)op = o0;
    *(float4*)(op + 4) = o1;
}

extern "C" void kernel_launch(void* const* d_in, const int* in_sizes, int n_in,
                              void* d_out, int out_size, void* d_ws, size_t ws_size,
                              hipStream_t stream) {
    const float* nodes = (const float*)d_in[0];
    const float* Cmat = (const float*)d_in[1];
    const float* Nmat = (const float*)d_in[2];
    const float* w = (const float*)d_in[4];
    const float* attn = (const float*)d_in[5];
    float* out = (float*)d_out;

    char* ws = (char*)d_ws;
    size_t off = 0;
    auto alloc = [&](size_t bytes) -> void* {
        void* p = ws + off;
        off += (bytes + 255) & ~(size_t)255;
        return p;
    };
    short* Z16 = (short*)alloc((size_t)BB * NN * DD * 2);  // 4 MB
    int* cur = (int*)alloc((size_t)BB * NN * 4);           // 16 KB -- contiguous with p1,p2
    float* p1 = (float*)alloc((size_t)BB * NN * 4);        // 16 KB
    float* p2 = (float*)alloc((size_t)BB * NN * 4);        // 16 KB
    int* sDst = (int*)alloc((size_t)BB * NN * SLOTS * 4);  // 1 MB

    hipMemsetAsync(cur, 0, (size_t)3 * BB * NN * 4, stream);  // cur+p1+p2
    k_mega<<<NGEMM + NEX, 256, 0, stream>>>(nodes, w, attn, Cmat, Nmat,
                                            Z16, p1, p2, cur, sDst);
    k_out<<<1024, 256, 0, stream>>>(cur, sDst, p1, p2, Z16, out);
}

// Round 12
// 51.627 us; speedup vs baseline: 1.0611x; 1.0611x over previous
//
#include <hip/hip_runtime.h>
#include <hip/hip_bf16.h>
#include <math.h>

#define BB 4
#define EE 8192
#define NN 1024
#define FF 512
#define DD 512
#define ALPHA 0.2f
#define SLOTS 64
#define NGEMM 256
#define NEX 8192   // 4 waves/block, 1 edge/wave

typedef __attribute__((ext_vector_type(8))) short short8;
typedef __attribute__((ext_vector_type(4))) float f32x4;

static __device__ __forceinline__ float leaky(float x) { return x > 0.f ? x : ALPHA * x; }

static __device__ __forceinline__ float wave_sum(float v) {
#pragma unroll
    for (int m = 32; m >= 1; m >>= 1) v += __shfl_xor(v, m);
    return v;
}
static __device__ __forceinline__ float wave_max(float v) {
#pragma unroll
    for (int m = 32; m >= 1; m >>= 1) v = fmaxf(v, __shfl_xor(v, m));
    return v;
}
static __device__ __forceinline__ short8 cvt8(float4 a, float4 b) {
    __hip_bfloat16 t[8];
    t[0] = __float2bfloat16(a.x); t[1] = __float2bfloat16(a.y);
    t[2] = __float2bfloat16(a.z); t[3] = __float2bfloat16(a.w);
    t[4] = __float2bfloat16(b.x); t[5] = __float2bfloat16(b.y);
    t[6] = __float2bfloat16(b.z); t[7] = __float2bfloat16(b.w);
    return *(short8*)t;
}
static __device__ __forceinline__ float b2f(short s) {
    unsigned u = ((unsigned)(unsigned short)s) << 16;
    float f;
    __builtin_memcpy(&f, &u, 4);
    return f;
}
static __device__ __forceinline__ short f2b(float f) {
    __hip_bfloat16 h = __float2bfloat16(f);
    short s;
    __builtin_memcpy(&s, &h, 2);
    return s;
}
// locate within a single 256-elem chunk; -1 if absent (wave-uniform result)
static __device__ __forceinline__ int find1(uint4 v, int lane) {
    unsigned nz = v.x | v.y | v.z | v.w;
    unsigned long long m = __ballot(nz != 0u);
    if (!m) return -1;
    int il = lane * 4 + (v.x ? 0 : (v.y ? 1 : (v.z ? 2 : 3)));
    return __shfl(il, (int)__ffsll(m) - 1);
}

// ---------------- K1 (mega): gemm (self-staged B, p-epilogue) + extract ----------------
#define BM 128
#define BN 64
#define BK 32
__global__ __launch_bounds__(256) void k_mega(const float* __restrict__ nodes,
                                              const float* __restrict__ w,
                                              const float* __restrict__ attn,
                                              const float* __restrict__ C,
                                              const float* __restrict__ Nm,
                                              short* __restrict__ Z16,
                                              float* __restrict__ p1, float* __restrict__ p2,
                                              int* __restrict__ cur, int* __restrict__ sDst) {
    __shared__ short As[BM][BK + 8];
    __shared__ short Bs[BN][BK + 8];
    int bx = blockIdx.x;
    int t = threadIdx.x;
    int lane = t & 63;
    if (bx < NGEMM) {
        // ---- GEMM: Z16 = bf16(nodes) @ bf16(w), B staged straight from w ----
        int m0 = (bx & 31) * BM;
        int n0 = (bx >> 5) * BN;
        int wid = t >> 6;
        int wm = wid & 1, wn = wid >> 1;
        int bc = t & 63, bkr = t >> 6;  // B staging: col, row-group
        f32x4 acc[4][2] = {};
        for (int k0 = 0; k0 < FF; k0 += BK) {
#pragma unroll
            for (int s = 0; s < 2; s++) {
                int cid = t + s * 256;
                int r = cid >> 2, cc = cid & 3;
                const float4* ap = (const float4*)&nodes[(size_t)(m0 + r) * FF + k0 + cc * 8];
                *(short8*)&As[r][cc * 8] = cvt8(ap[0], ap[1]);
            }
            {
                // stage B transposed: Bs[c][kk] = bf16(w[k0+kk][n0+c])
                short tmpb[8];
#pragma unroll
                for (int i = 0; i < 8; i++)
                    tmpb[i] = f2b(w[(size_t)(k0 + bkr * 8 + i) * DD + n0 + bc]);
                *(short8*)&Bs[bc][bkr * 8] = *(short8*)tmpb;
            }
            __syncthreads();
            short8 af[4];
            short8 bf[2];
#pragma unroll
            for (int m = 0; m < 4; m++)
                af[m] = *(const short8*)&As[wm * 64 + m * 16 + (lane & 15)][(lane >> 4) * 8];
#pragma unroll
            for (int n = 0; n < 2; n++)
                bf[n] = *(const short8*)&Bs[wn * 32 + n * 16 + (lane & 15)][(lane >> 4) * 8];
#pragma unroll
            for (int m = 0; m < 4; m++)
#pragma unroll
                for (int n = 0; n < 2; n++)
                    acc[m][n] = __builtin_amdgcn_mfma_f32_16x16x32_bf16(af[m], bf[n], acc[m][n], 0, 0, 0);
            __syncthreads();
        }
        // epilogue: Z16 store + p1/p2 partial dots (fp32 acc x attention cols)
        float a1c[2], a2c[2];
#pragma unroll
        for (int n = 0; n < 2; n++) {
            int col = n0 + wn * 32 + n * 16 + (lane & 15);
            a1c[n] = attn[col];
            a2c[n] = attn[DD + col];
        }
#pragma unroll
        for (int m = 0; m < 4; m++) {
#pragma unroll
            for (int n = 0; n < 2; n++)
#pragma unroll
                for (int r = 0; r < 4; r++) {
                    int row = m0 + wm * 64 + m * 16 + (lane >> 4) * 4 + r;
                    int col = n0 + wn * 32 + n * 16 + (lane & 15);
                    Z16[(size_t)row * DD + col] = f2b(acc[m][n][r]);
                }
#pragma unroll
            for (int r = 0; r < 4; r++) {
                float v1 = acc[m][0][r] * a1c[0] + acc[m][1][r] * a1c[1];
                float v2 = acc[m][0][r] * a2c[0] + acc[m][1][r] * a2c[1];
#pragma unroll
                for (int mm = 8; mm >= 1; mm >>= 1) {
                    v1 += __shfl_xor(v1, mm);
                    v2 += __shfl_xor(v2, mm);
                }
                if ((lane & 15) == 0) {
                    int row = m0 + wm * 64 + m * 16 + (lane >> 4) * 4 + r;
                    atomicAdd(&p1[row], v1);
                    atomicAdd(&p2[row], v2);
                }
            }
        }
        return;
    }
    // ---- extract + scatter: one wave per edge; bytes-minimal sequential 1KB chunk scan ----
    int widx = (bx - NGEMM) * 4 + (t >> 6);
    const uint4* rc = (const uint4*)(C + (size_t)widx * NN);
    const uint4* rn = (const uint4*)(Nm + (size_t)widx * NN);
    int s = -1, d = -1;
#pragma unroll 1
    for (int c = 0; c < 4 && ((s < 0) | (d < 0)); ++c) {
        uint4 va, vb;
        bool ns = s < 0, nd = d < 0;
        if (ns) va = rc[c * 64 + lane];
        if (nd) vb = rn[c * 64 + lane];
        if (ns) {
            int r = find1(va, lane);
            if (r >= 0) s = c * 256 + r;
        }
        if (nd) {
            int r = find1(vb, lane);
            if (r >= 0) d = c * 256 + r;
        }
    }
    if (lane == 0) {
        int b = widx >> 13;  // EE = 8192
        int row = b * NN + s;
        int pos = atomicAdd(&cur[row], 1);
        if (pos < SLOTS) sDst[row * SLOTS + pos] = d;
    }
}

// ---------------- K2: per-row softmax (exact keras-mask emulation) + output ----------------
__global__ __launch_bounds__(256) void k_out(const int* __restrict__ cur,
                                             const int* __restrict__ sDst,
                                             const float* __restrict__ p1,
                                             const float* __restrict__ p2,
                                             const short* __restrict__ Z16,
                                             float* __restrict__ out) {
    int rid = (blockIdx.x * 256 + threadIdx.x) >> 6;  // one wave per (b,i)
    int lane = threadIdx.x & 63;
    if (rid >= BB * NN) return;
    int K = cur[rid];
    K = K > SLOTS ? SLOTS : K;
    int base = rid * SLOTS;
    int b = rid >> 10;
    float* op = out + (size_t)rid * DD + lane * 8;
    if (K == 0) {
        float4 z4 = {0.f, 0.f, 0.f, 0.f};
        *(float4*)op = z4;
        *(float4*)(op + 4) = z4;
        return;
    }
    float p1row = p1[rid];
    int de = (lane < K) ? sDst[base + lane] : -1;
    float ae = (lane < K) ? leaky(p1row + p2[(b << 10) + de]) : 0.f;
    float S = 0.f;
    int c = 0, firstk = 64;
    for (int k = 0; k < K; k++) {
        int dk = __shfl(de, k);
        float ak = __shfl(ae, k);
        bool mt = (lane < K) && (dk == de);
        if (mt) {
            S += ak;
            c++;
            if (k < firstk) firstk = k;
        }
    }
    float logit = (lane < K) ? (S + (float)(c - 1) * 1e9f) : -INFINITY;
    float M = wave_max(logit);
    float contrib = (lane < K && firstk == lane) ? __expf(logit - M) : 0.f;
    float Dsum = wave_sum(contrib);
    float wgt = (lane < K) ? __expf(logit - M) / Dsum : 0.f;
    const short* Zb = Z16 + ((size_t)(b << 10)) * DD;
    float acc[8] = {0.f, 0.f, 0.f, 0.f, 0.f, 0.f, 0.f, 0.f};
#pragma unroll
    for (int k = 0; k < 32; k++) {
        if (k >= K) break;  // wave-uniform break
        int dj = __shfl(de, k);
        float wk = __shfl(wgt, k);
        short8 zv = *(const short8*)(Zb + (size_t)dj * DD + lane * 8);
#pragma unroll
        for (int j = 0; j < 8; j++) acc[j] += wk * b2f(zv[j]);
    }
    for (int k = 32; k < K; k++) {
        int dj = __shfl(de, k);
        float wk = __shfl(wgt, k);
        short8 zv = *(const short8*)(Zb + (size_t)dj * DD + lane * 8);
#pragma unroll
        for (int j = 0; j < 8; j++) acc[j] += wk * b2f(zv[j]);
    }
    float4 o0, o1;
    o0.x = leaky(acc[0]); o0.y = leaky(acc[1]); o0.z = leaky(acc[2]); o0.w = leaky(acc[3]);
    o1.x = leaky(acc[4]); o1.y = leaky(acc[5]); o1.z = leaky(acc[6]); o1.w = leaky(acc[7]);
    *(float4*)op = o0;
    *(float4*)(op + 4) = o1;
}

extern "C" void kernel_launch(void* const* d_in, const int* in_sizes, int n_in,
                              void* d_out, int out_size, void* d_ws, size_t ws_size,
                              hipStream_t stream) {
    const float* nodes = (const float*)d_in[0];
    const float* Cmat = (const float*)d_in[1];
    const float* Nmat = (const float*)d_in[2];
    const float* w = (const float*)d_in[4];
    const float* attn = (const float*)d_in[5];
    float* out = (float*)d_out;

    char* ws = (char*)d_ws;
    size_t off = 0;
    auto alloc = [&](size_t bytes) -> void* {
        void* p = ws + off;
        off += (bytes + 255) & ~(size_t)255;
        return p;
    };
    short* Z16 = (short*)alloc((size_t)BB * NN * DD * 2);  // 4 MB
    int* cur = (int*)alloc((size_t)BB * NN * 4);           // 16 KB -- contiguous with p1,p2
    float* p1 = (float*)alloc((size_t)BB * NN * 4);        // 16 KB
    float* p2 = (float*)alloc((size_t)BB * NN * 4);        // 16 KB
    int* sDst = (int*)alloc((size_t)BB * NN * SLOTS * 4);  // 1 MB

    hipMemsetAsync(cur, 0, (size_t)3 * BB * NN * 4, stream);  // cur+p1+p2
    k_mega<<<NGEMM + NEX, 256, 0, stream>>>(nodes, w, attn, Cmat, Nmat,
                                            Z16, p1, p2, cur, sDst);
    k_out<<<1024, 256, 0, stream>>>(cur, sDst, p1, p2, Z16, out);
}